// Round 2
// baseline (539.590 us; speedup 1.0000x reference)
//
#include <hip/hip_runtime.h>
#include <hip/hip_bf16.h>

// Problem constants (SpatialGraphConvolution_21251498180686)
#define NN 10000      // nodes per graph
#define EE 320000     // edges (before self-loops)
#define BB 4          // batch (graphs share edge structure)
#define F0 256        // input feat
#define F1 256        // hidden feat
#define F2 128        // output feat
#define ETOT (EE + NN)

// ---------------------------------------------------------------------------
// CSR build (by dst) — shared across graphs and layers.
// NOTE: harness delivers integer inputs as int32 (NOT the reference's int64).
// ---------------------------------------------------------------------------
__global__ void count_kernel(const int* __restrict__ ei, int* __restrict__ deg) {
    int id = blockIdx.x * blockDim.x + threadIdx.x;
    if (id >= ETOT) return;
    int dst = (id < EE) ? ei[EE + id] : (id - EE);
    atomicAdd(&deg[dst], 1);
}

__global__ void scan_kernel(const int* __restrict__ deg, int* __restrict__ rowstart) {
    __shared__ int buf[256];
    __shared__ int carry;
    int tid = threadIdx.x;
    if (tid == 0) carry = 0;
    __syncthreads();
    for (int base = 0; base < NN; base += 256) {
        int i = base + tid;
        int v = (i < NN) ? deg[i] : 0;
        buf[tid] = v;
        __syncthreads();
        for (int off = 1; off < 256; off <<= 1) {
            int t = (tid >= off) ? buf[tid - off] : 0;
            __syncthreads();
            buf[tid] += t;
            __syncthreads();
        }
        if (i < NN) rowstart[i] = carry + buf[tid] - v;  // exclusive
        __syncthreads();
        if (tid == 0) carry += buf[255];
        __syncthreads();
    }
    if (tid == 0) rowstart[NN] = carry;
}

__global__ void scatter_kernel(const int* __restrict__ ei,
                               const int* __restrict__ rowstart,
                               int* __restrict__ fill,
                               int* __restrict__ sorted_src) {
    int id = blockIdx.x * blockDim.x + threadIdx.x;
    if (id >= ETOT) return;
    int src, dst;
    if (id < EE) { src = ei[id]; dst = ei[EE + id]; }
    else         { src = dst = id - EE; }
    int pos = rowstart[dst] + atomicAdd(&fill[dst], 1);
    sorted_src[pos] = src;
}

// ---------------------------------------------------------------------------
// fp32 GEMM:  C[M,N] = A[M,K] * Bw[N,K]^T   (no fp32 MFMA on CDNA4 -> VALU)
// BM=128 BN=64 BK=16, 256 threads, 8x4 micro-tile
// ---------------------------------------------------------------------------
#define GBM 128
#define GBN 64
#define GBK 16
__global__ __launch_bounds__(256) void gemm_nt(const float* __restrict__ A,
                                               const float* __restrict__ Bw,
                                               float* __restrict__ C,
                                               int M, int N, int K) {
    __shared__ float As[GBK][GBM + 4];
    __shared__ float Bs[GBK][GBN + 4];
    int tid = threadIdx.x;
    int bm = blockIdx.x * GBM;
    int bn = blockIdx.y * GBN;
    int tx = tid & 15;   // N dir
    int ty = tid >> 4;   // M dir
    float acc[8][4];
#pragma unroll
    for (int i = 0; i < 8; i++)
#pragma unroll
        for (int j = 0; j < 4; j++) acc[i][j] = 0.f;

    for (int k0 = 0; k0 < K; k0 += GBK) {
        // A tile: 128x16 = 512 float4, 2 per thread
#pragma unroll
        for (int r = 0; r < 2; r++) {
            int f4 = tid + r * 256;
            int m = f4 >> 2;
            int k4 = (f4 & 3) * 4;
            int row = bm + m;
            float4 v = make_float4(0.f, 0.f, 0.f, 0.f);
            if (row < M) v = *(const float4*)(A + (size_t)row * K + k0 + k4);
            As[k4 + 0][m] = v.x; As[k4 + 1][m] = v.y;
            As[k4 + 2][m] = v.z; As[k4 + 3][m] = v.w;
        }
        // B tile: 64x16 = 256 float4, 1 per thread
        {
            int n = tid >> 2;
            int k4 = (tid & 3) * 4;
            float4 v = *(const float4*)(Bw + (size_t)(bn + n) * K + k0 + k4);
            Bs[k4 + 0][n] = v.x; Bs[k4 + 1][n] = v.y;
            Bs[k4 + 2][n] = v.z; Bs[k4 + 3][n] = v.w;
        }
        __syncthreads();
#pragma unroll
        for (int kk = 0; kk < GBK; kk++) {
            float a[8], b[4];
            *(float4*)&a[0] = *(const float4*)&As[kk][ty * 8];
            *(float4*)&a[4] = *(const float4*)&As[kk][ty * 8 + 4];
            *(float4*)&b[0] = *(const float4*)&Bs[kk][tx * 4];
#pragma unroll
            for (int i = 0; i < 8; i++)
#pragma unroll
                for (int j = 0; j < 4; j++) acc[i][j] += a[i] * b[j];
        }
        __syncthreads();
    }
#pragma unroll
    for (int i = 0; i < 8; i++) {
        int row = bm + ty * 8 + i;
        if (row < M) {
            float4 v = make_float4(acc[i][0], acc[i][1], acc[i][2], acc[i][3]);
            *(float4*)(C + (size_t)row * N + bn + tx * 4) = v;
        }
    }
}

// ---------------------------------------------------------------------------
// al kernel: per node (wave), al_s = h.a_src, al_d = h.a_dst
// ---------------------------------------------------------------------------
__global__ __launch_bounds__(256) void al_kernel(const float* __restrict__ h,
                                                 const float* __restrict__ asrc,
                                                 const float* __restrict__ adst,
                                                 float* __restrict__ als,
                                                 float* __restrict__ ald,
                                                 int F) {
    int wid = (blockIdx.x * blockDim.x + threadIdx.x) >> 6;  // 0..B*N-1
    int lane = threadIdx.x & 63;
    const float* hrow = h + (size_t)wid * F;
    float s = 0.f, d = 0.f;
    for (int f = lane; f < F; f += 64) {
        float v = hrow[f];
        s += v * asrc[f];
        d += v * adst[f];
    }
#pragma unroll
    for (int off = 32; off; off >>= 1) {
        s += __shfl_xor(s, off);
        d += __shfl_xor(d, off);
    }
    if (lane == 0) { als[wid] = s; ald[wid] = d; }
}

// ---------------------------------------------------------------------------
// Fused attention softmax + aggregate + bias + relu.
// One wave per (graph b, dst node n). F in {256,128}; V = F/64 floats/lane.
// ---------------------------------------------------------------------------
template <int F>
__global__ __launch_bounds__(256) void agg_kernel(const float* __restrict__ h,
                                                  const float* __restrict__ als,
                                                  const float* __restrict__ ald,
                                                  const int* __restrict__ rowstart,
                                                  const int* __restrict__ sorted_src,
                                                  const float* __restrict__ bias,
                                                  float* __restrict__ out) {
    constexpr int V = F / 64;
    typedef float fvec __attribute__((ext_vector_type(V)));

    int wid = (blockIdx.x * blockDim.x + threadIdx.x) >> 6;  // 0..B*N-1
    int lane = threadIdx.x & 63;
    int b = wid / NN;
    int n = wid - b * NN;

    const float* als_b = als + (size_t)b * NN;
    float aldn = ald[(size_t)b * NN + n];
    int rs = rowstart[n];
    int deg = rowstart[n + 1] - rs;

    // pass 1: max(e)
    float m = -INFINITY;
    for (int j = lane; j < deg; j += 64) {
        int s = sorted_src[rs + j];
        float e = als_b[s] + aldn;
        e = e > 0.f ? e : 0.2f * e;
        m = fmaxf(m, e);
    }
#pragma unroll
    for (int off = 32; off; off >>= 1) m = fmaxf(m, __shfl_xor(m, off));

    // pass 2: chunked — unnormalized weights + feature accumulation
    const float* hb = h + (size_t)b * NN * F;
    fvec acc;
#pragma unroll
    for (int u = 0; u < V; u++) acc[u] = 0.f;
    float sum = 0.f;
    int nchunk = (deg + 63) >> 6;
    for (int c = 0; c < nchunk; c++) {
        int j = (c << 6) + lane;
        float ex = 0.f;
        int srcj = 0;
        if (j < deg) {
            srcj = sorted_src[rs + j];
            float e = als_b[srcj] + aldn;
            e = e > 0.f ? e : 0.2f * e;
            ex = __expf(e - m);
        }
        sum += ex;
        int cnt = min(64, deg - (c << 6));
        for (int jj = 0; jj < cnt; jj++) {
            float sx = __shfl(ex, jj);
            int s = __shfl(srcj, jj);
            fvec hv = *(const fvec*)(hb + (size_t)s * F + lane * V);
#pragma unroll
            for (int u = 0; u < V; u++) acc[u] += sx * hv[u];
        }
    }
#pragma unroll
    for (int off = 32; off; off >>= 1) sum += __shfl_xor(sum, off);
    float inv = 1.0f / (sum + 1e-16f);

    fvec bv = *(const fvec*)(bias + lane * V);
    fvec r;
#pragma unroll
    for (int u = 0; u < V; u++) {
        float v = acc[u] * inv + bv[u];
        r[u] = fmaxf(v, 0.f);
    }
    *(fvec*)(out + (size_t)wid * F + lane * V) = r;
}

// ---------------------------------------------------------------------------
extern "C" void kernel_launch(void* const* d_in, const int* in_sizes, int n_in,
                              void* d_out, int out_size, void* d_ws, size_t ws_size,
                              hipStream_t stream) {
    const float* x     = (const float*)d_in[0];
    const int*   ei    = (const int*)d_in[1];   // int inputs arrive as int32
    const float* W0    = (const float*)d_in[2];
    const float* b0    = (const float*)d_in[3];
    const float* asrc0 = (const float*)d_in[4];
    const float* adst0 = (const float*)d_in[5];
    const float* W1    = (const float*)d_in[6];
    const float* b1    = (const float*)d_in[7];
    const float* asrc1 = (const float*)d_in[8];
    const float* adst1 = (const float*)d_in[9];
    float* outp = (float*)d_out;

    const int M = BB * NN;  // 40000

    // workspace layout (256B-aligned chunks), total ~84 MB
    size_t off = 0;
    char* base = (char*)d_ws;
    auto alloc = [&](size_t bytes) {
        void* p = base + off;
        off += (bytes + 255) & ~(size_t)255;
        return p;
    };
    int*   deg        = (int*)alloc((size_t)NN * 4);
    int*   fill       = (int*)alloc((size_t)NN * 4);
    int*   rowstart   = (int*)alloc((size_t)(NN + 1) * 4);
    int*   sorted_src = (int*)alloc((size_t)ETOT * 4);
    float* h          = (float*)alloc((size_t)M * F1 * 4);  // reused for layer-1 h
    float* out0       = (float*)alloc((size_t)M * F1 * 4);
    float* als        = (float*)alloc((size_t)M * 4);
    float* ald        = (float*)alloc((size_t)M * 4);

    hipMemsetAsync(deg, 0, (size_t)NN * 4, stream);
    hipMemsetAsync(fill, 0, (size_t)NN * 4, stream);

    int egrid = (ETOT + 255) / 256;
    count_kernel<<<egrid, 256, 0, stream>>>(ei, deg);
    scan_kernel<<<1, 256, 0, stream>>>(deg, rowstart);
    scatter_kernel<<<egrid, 256, 0, stream>>>(ei, rowstart, fill, sorted_src);

    int mtiles = (M + GBM - 1) / GBM;      // 313
    int wgrid = (M * 64) / 256;            // 10000 blocks = 1 wave per (b,node)

    // ----- layer 0 -----
    gemm_nt<<<dim3(mtiles, F1 / GBN), 256, 0, stream>>>(x, W0, h, M, F1, F0);
    al_kernel<<<wgrid, 256, 0, stream>>>(h, asrc0, adst0, als, ald, F1);
    agg_kernel<F1><<<wgrid, 256, 0, stream>>>(h, als, ald, rowstart, sorted_src, b0, out0);

    // ----- layer 1 -----
    gemm_nt<<<dim3(mtiles, F2 / GBN), 256, 0, stream>>>(out0, W1, h, M, F2, F1);
    al_kernel<<<wgrid, 256, 0, stream>>>(h, asrc1, adst1, als, ald, F2);
    agg_kernel<F2><<<wgrid, 256, 0, stream>>>(h, als, ald, rowstart, sorted_src, b1, outp);
}

// Round 3
// 459.454 us; speedup vs baseline: 1.1744x; 1.1744x over previous
//
#include <hip/hip_runtime.h>
#include <hip/hip_bf16.h>

// Problem constants (SpatialGraphConvolution_21251498180686)
#define NN 10000      // nodes per graph
#define EE 320000     // edges (before self-loops)
#define BB 4          // batch (graphs share edge structure)
#define F0 256        // input feat
#define F1 256        // hidden feat
#define F2 128        // output feat
#define ETOT (EE + NN)

typedef __attribute__((ext_vector_type(8))) short bf16x8;
typedef __attribute__((ext_vector_type(4))) float f32x4;

__device__ inline unsigned short f2bf_rn(float f) {
    unsigned int u = __float_as_uint(f);
    unsigned int r = (u + 0x7fffu + ((u >> 16) & 1u)) >> 16;
    return (unsigned short)r;
}
__device__ inline float bf2f(unsigned short s) {
    return __uint_as_float(((unsigned int)s) << 16);
}

// ---------------------------------------------------------------------------
// CSR build (by dst) — int inputs arrive as int32.
// ---------------------------------------------------------------------------
__global__ void count_kernel(const int* __restrict__ ei, int* __restrict__ deg) {
    int id = blockIdx.x * blockDim.x + threadIdx.x;
    if (id >= ETOT) return;
    int dst = (id < EE) ? ei[EE + id] : (id - EE);
    atomicAdd(&deg[dst], 1);
}

__global__ void scan_kernel(const int* __restrict__ deg, int* __restrict__ rowstart) {
    __shared__ int buf[256];
    __shared__ int carry;
    int tid = threadIdx.x;
    if (tid == 0) carry = 0;
    __syncthreads();
    for (int base = 0; base < NN; base += 256) {
        int i = base + tid;
        int v = (i < NN) ? deg[i] : 0;
        buf[tid] = v;
        __syncthreads();
        for (int off = 1; off < 256; off <<= 1) {
            int t = (tid >= off) ? buf[tid - off] : 0;
            __syncthreads();
            buf[tid] += t;
            __syncthreads();
        }
        if (i < NN) rowstart[i] = carry + buf[tid] - v;  // exclusive
        __syncthreads();
        if (tid == 0) carry += buf[255];
        __syncthreads();
    }
    if (tid == 0) rowstart[NN] = carry;
}

__global__ void scatter_kernel(const int* __restrict__ ei,
                               const int* __restrict__ rowstart,
                               int* __restrict__ fill,
                               int* __restrict__ sorted_src) {
    int id = blockIdx.x * blockDim.x + threadIdx.x;
    if (id >= ETOT) return;
    int src, dst;
    if (id < EE) { src = ei[id]; dst = ei[EE + id]; }
    else         { src = dst = id - EE; }
    int pos = rowstart[dst] + atomicAdd(&fill[dst], 1);
    sorted_src[pos] = src;
}

// ---------------------------------------------------------------------------
// Split a fp32 matrix into [hi | lo] bf16 halves: out2[r][0..K)=hi, [K..2K)=lo.
// a ≈ hi + lo with residual ~2^-17 relative.
// ---------------------------------------------------------------------------
__global__ __launch_bounds__(256) void conv_split(const float* __restrict__ in,
                                                  unsigned short* __restrict__ out2,
                                                  int rows, int K) {
    int q = K >> 2;
    int id = blockIdx.x * blockDim.x + threadIdx.x;
    if (id >= rows * q) return;
    int r = id / q;
    int c4 = (id - r * q) << 2;
    float4 v = *(const float4*)(in + (size_t)r * K + c4);
    ushort4 hi, lo;
    hi.x = f2bf_rn(v.x); lo.x = f2bf_rn(v.x - bf2f(hi.x));
    hi.y = f2bf_rn(v.y); lo.y = f2bf_rn(v.y - bf2f(hi.y));
    hi.z = f2bf_rn(v.z); lo.z = f2bf_rn(v.z - bf2f(hi.z));
    hi.w = f2bf_rn(v.w); lo.w = f2bf_rn(v.w - bf2f(hi.w));
    unsigned short* o = out2 + (size_t)r * 2 * K;
    *(ushort4*)(o + c4) = hi;
    *(ushort4*)(o + K + c4) = lo;
}

// ---------------------------------------------------------------------------
// Split-bf16 MFMA GEMM: C[M,N] fp32 = A[M,K] * B[N,K]^T using
// A2=[A_hi|A_lo], B2=[B_hi|B_lo] and 3 terms: hi*hi + lo*hi + hi*lo.
// Tile 128x128, 4 waves (2x2), each wave 64x64 = 4x4 MFMA 16x16x32 tiles.
// LDS rows padded to 40 shorts (80 B) -> 2-way bank aliasing only (free).
// ---------------------------------------------------------------------------
__global__ __launch_bounds__(256) void gemm_mfma(const unsigned short* __restrict__ A2,
                                                 const unsigned short* __restrict__ B2,
                                                 float* __restrict__ C,
                                                 int M, int N, int K) {
    __shared__ short As[128 * 40];
    __shared__ short Bs[128 * 40];
    int tid = threadIdx.x;
    int wave = tid >> 6, lane = tid & 63;
    int wm = wave & 1, wn = wave >> 1;
    int bm = blockIdx.x * 128, bn = blockIdx.y * 128;
    int lq = lane >> 4, lm = lane & 15;
    const int K2 = 2 * K;

    f32x4 acc[4][4];
#pragma unroll
    for (int i = 0; i < 4; i++)
#pragma unroll
        for (int j = 0; j < 4; j++) {
            acc[i][j][0] = 0.f; acc[i][j][1] = 0.f;
            acc[i][j][2] = 0.f; acc[i][j][3] = 0.f;
        }

    int sr = tid >> 2;         // 0..63 (staging row)
    int sc = (tid & 3) << 3;   // 0,8,16,24 (staging col, elements)

    for (int t = 0; t < 3; t++) {
        int aoff = (t == 1) ? K : 0;
        int boff = (t == 2) ? K : 0;
        for (int k0 = 0; k0 < K; k0 += 32) {
#pragma unroll
            for (int hh = 0; hh < 2; hh++) {
                int r = sr + hh * 64;
                uint4 va = make_uint4(0, 0, 0, 0);
                int grow = bm + r;
                if (grow < M)
                    va = *(const uint4*)(A2 + (size_t)grow * K2 + aoff + k0 + sc);
                *(uint4*)(As + r * 40 + sc) = va;
                uint4 vb = *(const uint4*)(B2 + (size_t)(bn + r) * K2 + boff + k0 + sc);
                *(uint4*)(Bs + r * 40 + sc) = vb;
            }
            __syncthreads();
            bf16x8 af[4], bfr[4];
#pragma unroll
            for (int i = 0; i < 4; i++) {
                af[i]  = *(const bf16x8*)(As + (wm * 64 + i * 16 + lm) * 40 + lq * 8);
                bfr[i] = *(const bf16x8*)(Bs + (wn * 64 + i * 16 + lm) * 40 + lq * 8);
            }
#pragma unroll
            for (int i = 0; i < 4; i++)
#pragma unroll
                for (int j = 0; j < 4; j++)
                    acc[i][j] = __builtin_amdgcn_mfma_f32_16x16x32_bf16(af[i], bfr[j], acc[i][j], 0, 0, 0);
            __syncthreads();
        }
    }
    // C/D layout: col = lane&15, row = (lane>>4)*4 + reg  [m89/m91 verified]
#pragma unroll
    for (int i = 0; i < 4; i++) {
        int rbase = bm + wm * 64 + i * 16 + lq * 4;
#pragma unroll
        for (int rr = 0; rr < 4; rr++) {
            int row = rbase + rr;
            if (row < M) {
#pragma unroll
                for (int j = 0; j < 4; j++)
                    C[(size_t)row * N + bn + wn * 64 + j * 16 + lm] = acc[i][j][rr];
            }
        }
    }
}

// ---------------------------------------------------------------------------
// al kernel: per node (wave), al_s = h.a_src, al_d = h.a_dst
// ---------------------------------------------------------------------------
__global__ __launch_bounds__(256) void al_kernel(const float* __restrict__ h,
                                                 const float* __restrict__ asrc,
                                                 const float* __restrict__ adst,
                                                 float* __restrict__ als,
                                                 float* __restrict__ ald,
                                                 int F) {
    int wid = (blockIdx.x * blockDim.x + threadIdx.x) >> 6;
    int lane = threadIdx.x & 63;
    const float* hrow = h + (size_t)wid * F;
    float s = 0.f, d = 0.f;
    for (int f = lane; f < F; f += 64) {
        float v = hrow[f];
        s += v * asrc[f];
        d += v * adst[f];
    }
#pragma unroll
    for (int off = 32; off; off >>= 1) {
        s += __shfl_xor(s, off);
        d += __shfl_xor(d, off);
    }
    if (lane == 0) { als[wid] = s; ald[wid] = d; }
}

// ---------------------------------------------------------------------------
// Fused attention softmax + aggregate + bias + relu.
// Max pass removed: e = als+ald is bounded (~|9|), exp(e) safe in fp32, and
// softmax is shift-invariant (eps=1e-16 negligible vs denom in both forms).
// Broadcast loop unrolled x4 -> 4 independent row-gathers in flight.
// OUTMODE 0: write fp32 [M][F].  OUTMODE 1: write split-bf16 [M][2F] (feeds
// the next layer's MFMA GEMM directly).
// ---------------------------------------------------------------------------
template <int F, int OUTMODE>
__global__ __launch_bounds__(256) void agg_kernel(const float* __restrict__ h,
                                                  const float* __restrict__ als,
                                                  const float* __restrict__ ald,
                                                  const int* __restrict__ rowstart,
                                                  const int* __restrict__ sorted_src,
                                                  const float* __restrict__ bias,
                                                  float* __restrict__ out,
                                                  unsigned short* __restrict__ out2) {
    constexpr int V = F / 64;
    typedef float fvec __attribute__((ext_vector_type(V)));

    int wid = (blockIdx.x * blockDim.x + threadIdx.x) >> 6;  // 0..B*N-1
    int lane = threadIdx.x & 63;
    int b = wid / NN;
    int n = wid - b * NN;

    const float* als_b = als + (size_t)b * NN;
    float aldn = ald[(size_t)b * NN + n];
    int rs = rowstart[n];
    int deg = rowstart[n + 1] - rs;
    const float* hb = h + (size_t)b * NN * F;

    fvec acc;
#pragma unroll
    for (int u = 0; u < V; u++) acc[u] = 0.f;
    float sum = 0.f;

    for (int c0 = 0; c0 < deg; c0 += 64) {
        int j = c0 + lane;
        float ex = 0.f;
        int srcj = 0;
        if (j < deg) {
            srcj = sorted_src[rs + j];
            float e = als_b[srcj] + aldn;
            e = e > 0.f ? e : 0.2f * e;
            ex = __expf(e);
        }
        sum += ex;
        int cnt = min(64, deg - c0);
        int jj = 0;
        for (; jj + 4 <= cnt; jj += 4) {
            int s0 = __shfl(srcj, jj),     s1 = __shfl(srcj, jj + 1);
            int s2 = __shfl(srcj, jj + 2), s3 = __shfl(srcj, jj + 3);
            float x0 = __shfl(ex, jj),     x1 = __shfl(ex, jj + 1);
            float x2 = __shfl(ex, jj + 2), x3 = __shfl(ex, jj + 3);
            fvec h0 = *(const fvec*)(hb + (size_t)s0 * F + lane * V);
            fvec h1 = *(const fvec*)(hb + (size_t)s1 * F + lane * V);
            fvec h2 = *(const fvec*)(hb + (size_t)s2 * F + lane * V);
            fvec h3 = *(const fvec*)(hb + (size_t)s3 * F + lane * V);
#pragma unroll
            for (int u = 0; u < V; u++) {
                acc[u] += x0 * h0[u];
                acc[u] += x1 * h1[u];
                acc[u] += x2 * h2[u];
                acc[u] += x3 * h3[u];
            }
        }
        for (; jj < cnt; jj++) {
            float sx = __shfl(ex, jj);
            int s = __shfl(srcj, jj);
            fvec hv = *(const fvec*)(hb + (size_t)s * F + lane * V);
#pragma unroll
            for (int u = 0; u < V; u++) acc[u] += sx * hv[u];
        }
    }
#pragma unroll
    for (int off = 32; off; off >>= 1) sum += __shfl_xor(sum, off);
    float inv = 1.0f / (sum + 1e-16f);

    fvec bv = *(const fvec*)(bias + lane * V);
    fvec r;
#pragma unroll
    for (int u = 0; u < V; u++) {
        float v = acc[u] * inv + bv[u];
        r[u] = fmaxf(v, 0.f);
    }
    if (OUTMODE == 0) {
        *(fvec*)(out + (size_t)wid * F + lane * V) = r;
    } else {
        // split-bf16 write (V must be 4 here: F=256)
        ushort4 hi, lo;
        hi.x = f2bf_rn(r[0]); lo.x = f2bf_rn(r[0] - bf2f(hi.x));
        hi.y = f2bf_rn(r[1]); lo.y = f2bf_rn(r[1] - bf2f(hi.y));
        hi.z = f2bf_rn(r[2]); lo.z = f2bf_rn(r[2] - bf2f(hi.z));
        hi.w = f2bf_rn(r[3]); lo.w = f2bf_rn(r[3] - bf2f(hi.w));
        unsigned short* o = out2 + (size_t)wid * 2 * F;
        *(ushort4*)(o + lane * 4) = hi;
        *(ushort4*)(o + F + lane * 4) = lo;
    }
}

// ---------------------------------------------------------------------------
extern "C" void kernel_launch(void* const* d_in, const int* in_sizes, int n_in,
                              void* d_out, int out_size, void* d_ws, size_t ws_size,
                              hipStream_t stream) {
    const float* x     = (const float*)d_in[0];
    const int*   ei    = (const int*)d_in[1];
    const float* W0    = (const float*)d_in[2];
    const float* b0    = (const float*)d_in[3];
    const float* asrc0 = (const float*)d_in[4];
    const float* adst0 = (const float*)d_in[5];
    const float* W1    = (const float*)d_in[6];
    const float* b1    = (const float*)d_in[7];
    const float* asrc1 = (const float*)d_in[8];
    const float* adst1 = (const float*)d_in[9];
    float* outp = (float*)d_out;

    const int M = BB * NN;  // 40000

    size_t off = 0;
    char* base = (char*)d_ws;
    auto alloc = [&](size_t bytes) {
        void* p = base + off;
        off += (bytes + 255) & ~(size_t)255;
        return p;
    };
    int*   deg        = (int*)alloc((size_t)NN * 4);
    int*   fill       = (int*)alloc((size_t)NN * 4);
    int*   rowstart   = (int*)alloc((size_t)(NN + 1) * 4);
    int*   sorted_src = (int*)alloc((size_t)ETOT * 4);
    unsigned short* A2  = (unsigned short*)alloc((size_t)M * 512 * 2);  // x split; reused as out0 split
    unsigned short* W02 = (unsigned short*)alloc((size_t)F1 * 512 * 2);
    unsigned short* W12 = (unsigned short*)alloc((size_t)F2 * 512 * 2);
    float* h          = (float*)alloc((size_t)M * F1 * 4);  // layer outputs (pre-agg)
    float* als        = (float*)alloc((size_t)M * 4);
    float* ald        = (float*)alloc((size_t)M * 4);

    hipMemsetAsync(deg, 0, (size_t)NN * 4, stream);
    hipMemsetAsync(fill, 0, (size_t)NN * 4, stream);

    int egrid = (ETOT + 255) / 256;
    count_kernel<<<egrid, 256, 0, stream>>>(ei, deg);
    scan_kernel<<<1, 256, 0, stream>>>(deg, rowstart);
    scatter_kernel<<<egrid, 256, 0, stream>>>(ei, rowstart, fill, sorted_src);

    int mtiles = (M + 127) / 128;          // 313
    int wgrid = (M * 64) / 256;            // 10000 blocks = 1 wave per (b,node)

    // conversions
    conv_split<<<(M * (F0 / 4) + 255) / 256, 256, 0, stream>>>(x, A2, M, F0);
    conv_split<<<(F1 * (F0 / 4) + 255) / 256, 256, 0, stream>>>(W0, W02, F1, F0);
    conv_split<<<(F2 * (F1 / 4) + 255) / 256, 256, 0, stream>>>(W1, W12, F2, F1);

    // ----- layer 0 -----
    gemm_mfma<<<dim3(mtiles, F1 / 128), 256, 0, stream>>>(A2, W02, h, M, F1, F0);
    al_kernel<<<wgrid, 256, 0, stream>>>(h, asrc0, adst0, als, ald, F1);
    agg_kernel<F1, 1><<<wgrid, 256, 0, stream>>>(h, als, ald, rowstart, sorted_src, b0,
                                                 nullptr, A2 /* out0 split, reuses A2 */);

    // ----- layer 1 -----
    gemm_mfma<<<dim3(mtiles, F2 / 128), 256, 0, stream>>>(A2, W12, h, M, F2, F1);
    al_kernel<<<wgrid, 256, 0, stream>>>(h, asrc1, adst1, als, ald, F2);
    agg_kernel<F2, 0><<<wgrid, 256, 0, stream>>>(h, als, ald, rowstart, sorted_src, b1,
                                                 outp, nullptr);
}

// Round 4
// 343.965 us; speedup vs baseline: 1.5687x; 1.3358x over previous
//
#include <hip/hip_runtime.h>
#include <hip/hip_bf16.h>

// Problem constants (SpatialGraphConvolution_21251498180686)
#define NN 10000      // nodes per graph
#define EE 320000     // edges (before self-loops)
#define BB 4          // batch (graphs share edge structure)
#define F0 256        // input feat
#define F1 256        // hidden feat
#define F2 128        // output feat
#define ETOT (EE + NN)

typedef __attribute__((ext_vector_type(8))) short bf16x8;
typedef __attribute__((ext_vector_type(4))) float f32x4;

__device__ inline unsigned short f2bf_rn(float f) {
    unsigned int u = __float_as_uint(f);
    unsigned int r = (u + 0x7fffu + ((u >> 16) & 1u)) >> 16;
    return (unsigned short)r;
}
__device__ inline float bf2f(unsigned short s) {
    return __uint_as_float(((unsigned int)s) << 16);
}

// ---------------------------------------------------------------------------
// CSR build (by dst) — int inputs arrive as int32.
// ---------------------------------------------------------------------------
__global__ void count_kernel(const int* __restrict__ ei, int* __restrict__ deg) {
    int id = blockIdx.x * blockDim.x + threadIdx.x;
    if (id >= ETOT) return;
    int dst = (id < EE) ? ei[EE + id] : (id - EE);
    atomicAdd(&deg[dst], 1);
}

// serial-per-thread chunks + one block scan (was: 320 barriers)
__global__ void scan_kernel(const int* __restrict__ deg, int* __restrict__ rowstart) {
    __shared__ int part[256];
    int t = threadIdx.x;
    const int CH = (NN + 255) / 256;  // 40
    int lo = t * CH, hi = min(lo + CH, NN);
    int s = 0;
    for (int i = lo; i < hi; i++) s += deg[i];
    part[t] = s;
    __syncthreads();
    for (int off = 1; off < 256; off <<= 1) {
        int v = (t >= off) ? part[t - off] : 0;
        __syncthreads();
        part[t] += v;
        __syncthreads();
    }
    int run = (t == 0) ? 0 : part[t - 1];
    for (int i = lo; i < hi; i++) { int d = deg[i]; rowstart[i] = run; run += d; }
    if (t == 255) rowstart[NN] = run;
}

__global__ void scatter_kernel(const int* __restrict__ ei,
                               const int* __restrict__ rowstart,
                               int* __restrict__ fill,
                               int* __restrict__ sorted_src) {
    int id = blockIdx.x * blockDim.x + threadIdx.x;
    if (id >= ETOT) return;
    int src, dst;
    if (id < EE) { src = ei[id]; dst = ei[EE + id]; }
    else         { src = dst = id - EE; }
    int pos = rowstart[dst] + atomicAdd(&fill[dst], 1);
    sorted_src[pos] = src;
}

// ---------------------------------------------------------------------------
// Split a fp32 matrix into [hi | lo] bf16 halves: out2[r][0..K)=hi, [K..2K)=lo.
// ---------------------------------------------------------------------------
__global__ __launch_bounds__(256) void conv_split(const float* __restrict__ in,
                                                  unsigned short* __restrict__ out2,
                                                  int rows, int K) {
    int q = K >> 2;
    int id = blockIdx.x * blockDim.x + threadIdx.x;
    if (id >= rows * q) return;
    int r = id / q;
    int c4 = (id - r * q) << 2;
    float4 v = *(const float4*)(in + (size_t)r * K + c4);
    ushort4 hi, lo;
    hi.x = f2bf_rn(v.x); lo.x = f2bf_rn(v.x - bf2f(hi.x));
    hi.y = f2bf_rn(v.y); lo.y = f2bf_rn(v.y - bf2f(hi.y));
    hi.z = f2bf_rn(v.z); lo.z = f2bf_rn(v.z - bf2f(hi.z));
    hi.w = f2bf_rn(v.w); lo.w = f2bf_rn(v.w - bf2f(hi.w));
    unsigned short* o = out2 + (size_t)r * 2 * K;
    *(ushort4*)(o + c4) = hi;
    *(ushort4*)(o + K + c4) = lo;
}

// ---------------------------------------------------------------------------
// Split-bf16 MFMA GEMM: C[M,N] bf16 = A[M,K]*B[N,K]^T, 3 terms hi*hi+lo*hi+hi*lo.
// Tile 128x128, 4 waves (2x2), wave 64x64 = 4x4 MFMA 16x16x32 tiles.
// Output written as plain bf16 (consumed by al/agg gather only).
// ---------------------------------------------------------------------------
__global__ __launch_bounds__(256) void gemm_mfma(const unsigned short* __restrict__ A2,
                                                 const unsigned short* __restrict__ B2,
                                                 unsigned short* __restrict__ C,
                                                 int M, int N, int K) {
    __shared__ short As[128 * 40];
    __shared__ short Bs[128 * 40];
    int tid = threadIdx.x;
    int wave = tid >> 6, lane = tid & 63;
    int wm = wave & 1, wn = wave >> 1;
    int bm = blockIdx.x * 128, bn = blockIdx.y * 128;
    int lq = lane >> 4, lm = lane & 15;
    const int K2 = 2 * K;

    f32x4 acc[4][4];
#pragma unroll
    for (int i = 0; i < 4; i++)
#pragma unroll
        for (int j = 0; j < 4; j++) {
            acc[i][j][0] = 0.f; acc[i][j][1] = 0.f;
            acc[i][j][2] = 0.f; acc[i][j][3] = 0.f;
        }

    int sr = tid >> 2;         // staging row 0..63
    int sc = (tid & 3) << 3;   // staging col: 0,8,16,24

    for (int t = 0; t < 3; t++) {
        int aoff = (t == 1) ? K : 0;
        int boff = (t == 2) ? K : 0;
        for (int k0 = 0; k0 < K; k0 += 32) {
#pragma unroll
            for (int hh = 0; hh < 2; hh++) {
                int r = sr + hh * 64;
                uint4 va = make_uint4(0, 0, 0, 0);
                int grow = bm + r;
                if (grow < M)
                    va = *(const uint4*)(A2 + (size_t)grow * K2 + aoff + k0 + sc);
                *(uint4*)(As + r * 40 + sc) = va;
                uint4 vb = *(const uint4*)(B2 + (size_t)(bn + r) * K2 + boff + k0 + sc);
                *(uint4*)(Bs + r * 40 + sc) = vb;
            }
            __syncthreads();
            bf16x8 af[4], bfr[4];
#pragma unroll
            for (int i = 0; i < 4; i++) {
                af[i]  = *(const bf16x8*)(As + (wm * 64 + i * 16 + lm) * 40 + lq * 8);
                bfr[i] = *(const bf16x8*)(Bs + (wn * 64 + i * 16 + lm) * 40 + lq * 8);
            }
#pragma unroll
            for (int i = 0; i < 4; i++)
#pragma unroll
                for (int j = 0; j < 4; j++)
                    acc[i][j] = __builtin_amdgcn_mfma_f32_16x16x32_bf16(af[i], bfr[j], acc[i][j], 0, 0, 0);
            __syncthreads();
        }
    }
    // C/D layout: col = lane&15, row = (lane>>4)*4 + reg
#pragma unroll
    for (int i = 0; i < 4; i++) {
        int rbase = bm + wm * 64 + i * 16 + lq * 4;
#pragma unroll
        for (int rr = 0; rr < 4; rr++) {
            int row = rbase + rr;
            if (row < M) {
#pragma unroll
                for (int j = 0; j < 4; j++)
                    C[(size_t)row * N + bn + wn * 64 + j * 16 + lm] = f2bf_rn(acc[i][j][rr]);
            }
        }
    }
}

// ---------------------------------------------------------------------------
// al kernel (bf16 h): per node (wave), al_s = h.a_src, al_d = h.a_dst
// ---------------------------------------------------------------------------
template <int F>
__global__ __launch_bounds__(256) void al_kernel(const unsigned short* __restrict__ h,
                                                 const float* __restrict__ asrc,
                                                 const float* __restrict__ adst,
                                                 float* __restrict__ als,
                                                 float* __restrict__ ald) {
    constexpr int V = F / 64;
    typedef unsigned short usv __attribute__((ext_vector_type(V)));
    int wid = (blockIdx.x * blockDim.x + threadIdx.x) >> 6;
    int lane = threadIdx.x & 63;
    usv hv = *(const usv*)(h + (size_t)wid * F + lane * V);
    float s = 0.f, d = 0.f;
#pragma unroll
    for (int u = 0; u < V; u++) {
        float v = bf2f(hv[u]);
        s += v * asrc[lane * V + u];
        d += v * adst[lane * V + u];
    }
#pragma unroll
    for (int off = 32; off; off >>= 1) {
        s += __shfl_xor(s, off);
        d += __shfl_xor(d, off);
    }
    if (lane == 0) { als[wid] = s; ald[wid] = d; }
}

// ---------------------------------------------------------------------------
// Fused attention softmax + aggregate + bias + relu (bf16 h gather).
// One wave per (graph b, dst node n). Main loop: 16-wide load bursts into a
// fully-unrolled register buffer (~16 loads in flight). Tail: 4-wide padded
// groups (pad slots have w=0, srcj=0 -> harmless L1-hot loads of row 0).
// OUTMODE 0: fp32 out.  OUTMODE 1: split-bf16 [M][2F] feeding next GEMM.
// ---------------------------------------------------------------------------
template <int F, int OUTMODE>
__global__ __launch_bounds__(256) void agg_kernel(const unsigned short* __restrict__ h,
                                                  const float* __restrict__ als,
                                                  const float* __restrict__ ald,
                                                  const int* __restrict__ rowstart,
                                                  const int* __restrict__ sorted_src,
                                                  const float* __restrict__ bias,
                                                  float* __restrict__ out,
                                                  unsigned short* __restrict__ out2) {
    constexpr int V = F / 64;
    typedef unsigned short usv __attribute__((ext_vector_type(V)));
    typedef float fvec __attribute__((ext_vector_type(V)));

    int wid = (blockIdx.x * blockDim.x + threadIdx.x) >> 6;  // 0..B*N-1
    int lane = threadIdx.x & 63;
    int b = wid / NN;
    int n = wid - b * NN;

    const float* als_b = als + (size_t)b * NN;
    float aldn = ald[(size_t)b * NN + n];
    int rs = rowstart[n];
    int deg = rowstart[n + 1] - rs;
    const unsigned short* hb = h + (size_t)b * NN * F;

    fvec acc;
#pragma unroll
    for (int u = 0; u < V; u++) acc[u] = 0.f;
    float sum = 0.f;

    for (int c0 = 0; c0 < deg; c0 += 64) {
        int j = c0 + lane;
        float ex = 0.f;
        int srcj = 0;
        if (j < deg) {
            srcj = sorted_src[rs + j];
            float e = als_b[srcj] + aldn;
            e = e > 0.f ? e : 0.2f * e;
            ex = __expf(e);
        }
        sum += ex;
        int cnt = min(64, deg - c0);

        int nfull = cnt >> 4;  // full groups of 16 (all real edges)
        for (int g = 0; g < nfull; g++) {
            int bse = g << 4;
            int s[16]; float w[16];
#pragma unroll
            for (int i = 0; i < 16; i++) {
                s[i] = __shfl(srcj, bse + i);
                w[i] = __shfl(ex, bse + i);
            }
            usv r[16];
#pragma unroll
            for (int i = 0; i < 16; i++)
                r[i] = *(const usv*)(hb + (size_t)s[i] * F + lane * V);
#pragma unroll
            for (int i = 0; i < 16; i++)
#pragma unroll
                for (int u = 0; u < V; u++) acc[u] += w[i] * bf2f(r[i][u]);
        }
        // tail: 4-wide, zero-padded (shfl index < 64 always; pad lanes have ex=0)
        for (int bse = nfull << 4; bse < cnt; bse += 4) {
            int s[4]; float w[4];
#pragma unroll
            for (int i = 0; i < 4; i++) {
                s[i] = __shfl(srcj, bse + i);
                w[i] = __shfl(ex, bse + i);
            }
            usv r[4];
#pragma unroll
            for (int i = 0; i < 4; i++)
                r[i] = *(const usv*)(hb + (size_t)s[i] * F + lane * V);
#pragma unroll
            for (int i = 0; i < 4; i++)
#pragma unroll
                for (int u = 0; u < V; u++) acc[u] += w[i] * bf2f(r[i][u]);
        }
    }
#pragma unroll
    for (int off = 32; off; off >>= 1) sum += __shfl_xor(sum, off);
    float inv = 1.0f / (sum + 1e-16f);

    fvec r;
#pragma unroll
    for (int u = 0; u < V; u++) {
        float v = acc[u] * inv + bias[lane * V + u];
        r[u] = fmaxf(v, 0.f);
    }
    if (OUTMODE == 0) {
        *(fvec*)(out + (size_t)wid * F + lane * V) = r;
    } else {
        // split-bf16 write (F=256, V=4)
        ushort4 hi, lo;
        hi.x = f2bf_rn(r[0]); lo.x = f2bf_rn(r[0] - bf2f(hi.x));
        hi.y = f2bf_rn(r[1]); lo.y = f2bf_rn(r[1] - bf2f(hi.y));
        hi.z = f2bf_rn(r[2]); lo.z = f2bf_rn(r[2] - bf2f(hi.z));
        hi.w = f2bf_rn(r[3]); lo.w = f2bf_rn(r[3] - bf2f(hi.w));
        unsigned short* o = out2 + (size_t)wid * 2 * F;
        *(ushort4*)(o + lane * 4) = hi;
        *(ushort4*)(o + F + lane * 4) = lo;
    }
}

// ---------------------------------------------------------------------------
extern "C" void kernel_launch(void* const* d_in, const int* in_sizes, int n_in,
                              void* d_out, int out_size, void* d_ws, size_t ws_size,
                              hipStream_t stream) {
    const float* x     = (const float*)d_in[0];
    const int*   ei    = (const int*)d_in[1];
    const float* W0    = (const float*)d_in[2];
    const float* b0    = (const float*)d_in[3];
    const float* asrc0 = (const float*)d_in[4];
    const float* adst0 = (const float*)d_in[5];
    const float* W1    = (const float*)d_in[6];
    const float* b1    = (const float*)d_in[7];
    const float* asrc1 = (const float*)d_in[8];
    const float* adst1 = (const float*)d_in[9];
    float* outp = (float*)d_out;

    const int M = BB * NN;  // 40000

    size_t off = 0;
    char* base = (char*)d_ws;
    auto alloc = [&](size_t bytes) {
        void* p = base + off;
        off += (bytes + 255) & ~(size_t)255;
        return p;
    };
    int*   deg        = (int*)alloc((size_t)NN * 4);
    int*   fill       = (int*)alloc((size_t)NN * 4);
    int*   rowstart   = (int*)alloc((size_t)(NN + 1) * 4);
    int*   sorted_src = (int*)alloc((size_t)ETOT * 4);
    unsigned short* A2  = (unsigned short*)alloc((size_t)M * 512 * 2);  // x-split; reused as out0-split
    unsigned short* W02 = (unsigned short*)alloc((size_t)F1 * 512 * 2);
    unsigned short* W12 = (unsigned short*)alloc((size_t)F2 * 512 * 2);
    unsigned short* h   = (unsigned short*)alloc((size_t)M * F1 * 2);   // bf16 pre-agg features
    float* als        = (float*)alloc((size_t)M * 4);
    float* ald        = (float*)alloc((size_t)M * 4);

    hipMemsetAsync(deg, 0, (size_t)NN * 4, stream);
    hipMemsetAsync(fill, 0, (size_t)NN * 4, stream);

    int egrid = (ETOT + 255) / 256;
    count_kernel<<<egrid, 256, 0, stream>>>(ei, deg);
    scan_kernel<<<1, 256, 0, stream>>>(deg, rowstart);
    scatter_kernel<<<egrid, 256, 0, stream>>>(ei, rowstart, fill, sorted_src);

    int mtiles = (M + 127) / 128;          // 313
    int wgrid = (M * 64) / 256;            // 1 wave per (b,node)

    conv_split<<<(M * (F0 / 4) + 255) / 256, 256, 0, stream>>>(x, A2, M, F0);
    conv_split<<<(F1 * (F0 / 4) + 255) / 256, 256, 0, stream>>>(W0, W02, F1, F0);
    conv_split<<<(F2 * (F1 / 4) + 255) / 256, 256, 0, stream>>>(W1, W12, F2, F1);

    // ----- layer 0 -----
    gemm_mfma<<<dim3(mtiles, F1 / 128), 256, 0, stream>>>(A2, W02, h, M, F1, F0);
    al_kernel<F1><<<wgrid, 256, 0, stream>>>(h, asrc0, adst0, als, ald);
    agg_kernel<F1, 1><<<wgrid, 256, 0, stream>>>(h, als, ald, rowstart, sorted_src, b0,
                                                 nullptr, A2 /* out0 split */);

    // ----- layer 1 -----
    gemm_mfma<<<dim3(mtiles, F2 / 128), 256, 0, stream>>>(A2, W12, h, M, F2, F1);
    al_kernel<F2><<<wgrid, 256, 0, stream>>>(h, asrc1, adst1, als, ald);
    agg_kernel<F2, 0><<<wgrid, 256, 0, stream>>>(h, als, ald, rowstart, sorted_src, b1,
                                                 outp, nullptr);
}

// Round 6
// 340.672 us; speedup vs baseline: 1.5839x; 1.0097x over previous
//
#include <hip/hip_runtime.h>
#include <hip/hip_bf16.h>

// Problem constants (SpatialGraphConvolution_21251498180686)
#define NN 10000      // nodes per graph
#define EE 320000     // edges (before self-loops)
#define BB 4          // batch (graphs share edge structure)
#define F0 256        // input feat
#define F1 256        // hidden feat
#define F2 128        // output feat
#define ETOT (EE + NN)

typedef __attribute__((ext_vector_type(8))) short bf16x8;
typedef __attribute__((ext_vector_type(4))) float f32x4;

__device__ inline unsigned short f2bf_rn(float f) {
    unsigned int u = __float_as_uint(f);
    unsigned int r = (u + 0x7fffu + ((u >> 16) & 1u)) >> 16;
    return (unsigned short)r;
}
__device__ inline float bf2f(unsigned short s) {
    return __uint_as_float(((unsigned int)s) << 16);
}

// async 16B global -> LDS (direct-to-shared DMA, vmcnt-tracked)
__device__ __forceinline__ void gload16(const void* g, void* lds) {
    __builtin_amdgcn_global_load_lds(
        (const __attribute__((address_space(1))) unsigned int*)g,
        (__attribute__((address_space(3))) unsigned int*)lds, 16, 0, 0);
}

// ---------------------------------------------------------------------------
// CSR build (by dst) — int inputs arrive as int32.
// ---------------------------------------------------------------------------
__global__ void count_kernel(const int* __restrict__ ei, int* __restrict__ deg) {
    int id = blockIdx.x * blockDim.x + threadIdx.x;
    if (id >= ETOT) return;
    int dst = (id < EE) ? ei[EE + id] : (id - EE);
    atomicAdd(&deg[dst], 1);
}

__global__ void scan_kernel(const int* __restrict__ deg, int* __restrict__ rowstart) {
    __shared__ int part[256];
    int t = threadIdx.x;
    const int CH = (NN + 255) / 256;  // 40
    int lo = t * CH, hi = min(lo + CH, NN);
    int s = 0;
    for (int i = lo; i < hi; i++) s += deg[i];
    part[t] = s;
    __syncthreads();
    for (int off = 1; off < 256; off <<= 1) {
        int v = (t >= off) ? part[t - off] : 0;
        __syncthreads();
        part[t] += v;
        __syncthreads();
    }
    int run = (t == 0) ? 0 : part[t - 1];
    for (int i = lo; i < hi; i++) { int d = deg[i]; rowstart[i] = run; run += d; }
    if (t == 255) rowstart[NN] = run;
}

__global__ void scatter_kernel(const int* __restrict__ ei,
                               const int* __restrict__ rowstart,
                               int* __restrict__ fill,
                               int* __restrict__ sorted_src) {
    int id = blockIdx.x * blockDim.x + threadIdx.x;
    if (id >= ETOT) return;
    int src, dst;
    if (id < EE) { src = ei[id]; dst = ei[EE + id]; }
    else         { src = dst = id - EE; }
    int pos = rowstart[dst] + atomicAdd(&fill[dst], 1);
    sorted_src[pos] = src;
}

// ---------------------------------------------------------------------------
// Split a fp32 matrix into [hi | lo] bf16 halves: out2[r][0..K)=hi, [K..2K)=lo.
// ---------------------------------------------------------------------------
__global__ __launch_bounds__(256) void conv_split(const float* __restrict__ in,
                                                  unsigned short* __restrict__ out2,
                                                  int rows, int K) {
    int q = K >> 2;
    int id = blockIdx.x * blockDim.x + threadIdx.x;
    if (id >= rows * q) return;
    int r = id / q;
    int c4 = (id - r * q) << 2;
    float4 v = *(const float4*)(in + (size_t)r * K + c4);
    ushort4 hi, lo;
    hi.x = f2bf_rn(v.x); lo.x = f2bf_rn(v.x - bf2f(hi.x));
    hi.y = f2bf_rn(v.y); lo.y = f2bf_rn(v.y - bf2f(hi.y));
    hi.z = f2bf_rn(v.z); lo.z = f2bf_rn(v.z - bf2f(hi.z));
    hi.w = f2bf_rn(v.w); lo.w = f2bf_rn(v.w - bf2f(hi.w));
    unsigned short* o = out2 + (size_t)r * 2 * K;
    *(ushort4*)(o + c4) = hi;
    *(ushort4*)(o + K + c4) = lo;
}

// ---------------------------------------------------------------------------
// Split-bf16 MFMA GEMM, m97-style: C[M,N] bf16 = A[M,K]*B[N,K]^T, 3 terms.
// Tile 128x128, 4 waves (2x2), wave 64x64 = 4x4 MFMA 16x16x32 tiles.
// Staging: global_load_lds 16B into unpadded K-major LDS (wave-uniform
// base + lane*16 — tid-linear mapping satisfies this). OOB A-rows -> zero page.
// Epilogue: acc -> LDS (pitch 136 shorts) -> coalesced uint4 stores, two
// 64-row halves; each half is 64 rows x 16 uint4 = 1024 stores (r<4 loop).
// ---------------------------------------------------------------------------
__global__ __launch_bounds__(256) void gemm_mfma(const unsigned short* __restrict__ A2,
                                                 const unsigned short* __restrict__ B2,
                                                 unsigned short* __restrict__ C,
                                                 const unsigned short* __restrict__ zp,
                                                 int M, int N, int K) {
    __shared__ unsigned short sbuf[8704];           // max(As+Bs = 8192, Cs = 64*136)
    unsigned short* As = sbuf;                      // [128][32]
    unsigned short* Bs = sbuf + 4096;               // [128][32]
    int tid = threadIdx.x;
    int wave = tid >> 6, lane = tid & 63;
    int wm = wave & 1, wn = wave >> 1;
    int bm = blockIdx.x * 128, bn = blockIdx.y * 128;
    int lq = lane >> 4, lm = lane & 15;
    const int K2 = 2 * K;

    f32x4 acc[4][4];
#pragma unroll
    for (int i = 0; i < 4; i++)
#pragma unroll
        for (int j = 0; j < 4; j++) {
            acc[i][j][0] = 0.f; acc[i][j][1] = 0.f;
            acc[i][j][2] = 0.f; acc[i][j][3] = 0.f;
        }

    // staging: linear16 = round*256 + tid; row = linear16>>2, col16 = linear16&3
    int r0 = tid >> 2;              // rows 0..63 (round 1 adds 64)
    int csh = (tid & 3) << 3;       // col in shorts: 0,8,16,24
    const unsigned short* aP0 = ((bm + r0) < M ? A2 + (size_t)(bm + r0) * K2 : zp) + csh;
    const unsigned short* aP1 = ((bm + r0 + 64) < M ? A2 + (size_t)(bm + r0 + 64) * K2 : zp) + csh;
    const unsigned short* bP0 = B2 + (size_t)(bn + r0) * K2 + csh;
    const unsigned short* bP1 = B2 + (size_t)(bn + r0 + 64) * K2 + csh;
    unsigned short* ldsA0 = As + tid * 8;
    unsigned short* ldsA1 = As + (256 + tid) * 8;
    unsigned short* ldsB0 = Bs + tid * 8;
    unsigned short* ldsB1 = Bs + (256 + tid) * 8;

    for (int t = 0; t < 3; t++) {
        int aoff = (t == 1) ? K : 0;   // term order: hi*hi, lo*hi, hi*lo
        int boff = (t == 2) ? K : 0;
        for (int k0 = 0; k0 < K; k0 += 32) {
            gload16(aP0 + aoff + k0, ldsA0);
            gload16(aP1 + aoff + k0, ldsA1);
            gload16(bP0 + boff + k0, ldsB0);
            gload16(bP1 + boff + k0, ldsB1);
            __syncthreads();   // drains vmcnt (global_load_lds) before LDS reads
            bf16x8 af[4], bfr[4];
#pragma unroll
            for (int i = 0; i < 4; i++) {
                af[i]  = *(const bf16x8*)(As + (wm * 64 + i * 16 + lm) * 32 + lq * 8);
                bfr[i] = *(const bf16x8*)(Bs + (wn * 64 + i * 16 + lm) * 32 + lq * 8);
            }
#pragma unroll
            for (int i = 0; i < 4; i++)
#pragma unroll
                for (int j = 0; j < 4; j++)
                    acc[i][j] = __builtin_amdgcn_mfma_f32_16x16x32_bf16(af[i], bfr[j], acc[i][j], 0, 0, 0);
            __syncthreads();   // LDS reuse next chunk
        }
    }

    // Epilogue: C/D layout col = lane&15, row = (lane>>4)*4 + reg.
    unsigned short* Cs = sbuf;   // [64][136]
    for (int h = 0; h < 2; h++) {
        __syncthreads();
        if (wm == h) {
#pragma unroll
            for (int i = 0; i < 4; i++) {
                int rbase = i * 16 + lq * 4;
#pragma unroll
                for (int rr = 0; rr < 4; rr++) {
#pragma unroll
                    for (int j = 0; j < 4; j++)
                        Cs[(rbase + rr) * 136 + wn * 64 + j * 16 + lm] = f2bf_rn(acc[i][j][rr]);
                }
            }
        }
        __syncthreads();
#pragma unroll
        for (int r = 0; r < 4; r++) {
            int u = r * 256 + tid;           // 0..1023
            int row_l = u >> 4, q = u & 15;  // 64 rows x 16 uint4 (128 shorts)
            int row_g = bm + h * 64 + row_l;
            if (row_g < M) {
                uint4 v = *(const uint4*)(Cs + row_l * 136 + q * 8);
                *(uint4*)(C + (size_t)row_g * N + bn + q * 8) = v;
            }
        }
    }
}

// ---------------------------------------------------------------------------
// al kernel (bf16 h): per node (wave), al_s = h.a_src, al_d = h.a_dst
// ---------------------------------------------------------------------------
template <int F>
__global__ __launch_bounds__(256) void al_kernel(const unsigned short* __restrict__ h,
                                                 const float* __restrict__ asrc,
                                                 const float* __restrict__ adst,
                                                 float* __restrict__ als,
                                                 float* __restrict__ ald) {
    constexpr int V = F / 64;
    typedef unsigned short usv __attribute__((ext_vector_type(V)));
    int wid = (blockIdx.x * blockDim.x + threadIdx.x) >> 6;
    int lane = threadIdx.x & 63;
    usv hv = *(const usv*)(h + (size_t)wid * F + lane * V);
    float s = 0.f, d = 0.f;
#pragma unroll
    for (int u = 0; u < V; u++) {
        float v = bf2f(hv[u]);
        s += v * asrc[lane * V + u];
        d += v * adst[lane * V + u];
    }
#pragma unroll
    for (int off = 32; off; off >>= 1) {
        s += __shfl_xor(s, off);
        d += __shfl_xor(d, off);
    }
    if (lane == 0) { als[wid] = s; ald[wid] = d; }
}

// ---------------------------------------------------------------------------
// Fused attention softmax + aggregate + bias + relu (bf16 h gather).
// One wave per (graph b, dst node n); 16-wide load bursts for MLP.
// OUTMODE 0: fp32 out.  OUTMODE 1: split-bf16 [M][2F] feeding next GEMM.
// ---------------------------------------------------------------------------
template <int F, int OUTMODE>
__global__ __launch_bounds__(256) void agg_kernel(const unsigned short* __restrict__ h,
                                                  const float* __restrict__ als,
                                                  const float* __restrict__ ald,
                                                  const int* __restrict__ rowstart,
                                                  const int* __restrict__ sorted_src,
                                                  const float* __restrict__ bias,
                                                  float* __restrict__ out,
                                                  unsigned short* __restrict__ out2) {
    constexpr int V = F / 64;
    typedef unsigned short usv __attribute__((ext_vector_type(V)));
    typedef float fvec __attribute__((ext_vector_type(V)));

    int wid = (blockIdx.x * blockDim.x + threadIdx.x) >> 6;  // 0..B*N-1
    int lane = threadIdx.x & 63;
    int b = wid / NN;
    int n = wid - b * NN;

    const float* als_b = als + (size_t)b * NN;
    float aldn = ald[(size_t)b * NN + n];
    int rs = rowstart[n];
    int deg = rowstart[n + 1] - rs;
    const unsigned short* hb = h + (size_t)b * NN * F;

    fvec acc;
#pragma unroll
    for (int u = 0; u < V; u++) acc[u] = 0.f;
    float sum = 0.f;

    for (int c0 = 0; c0 < deg; c0 += 64) {
        int j = c0 + lane;
        float ex = 0.f;
        int srcj = 0;
        if (j < deg) {
            srcj = sorted_src[rs + j];
            float e = als_b[srcj] + aldn;
            e = e > 0.f ? e : 0.2f * e;
            ex = __expf(e);
        }
        sum += ex;
        int cnt = min(64, deg - c0);

        int nfull = cnt >> 4;
        for (int g = 0; g < nfull; g++) {
            int bse = g << 4;
            int s[16]; float w[16];
#pragma unroll
            for (int i = 0; i < 16; i++) {
                s[i] = __shfl(srcj, bse + i);
                w[i] = __shfl(ex, bse + i);
            }
            usv r[16];
#pragma unroll
            for (int i = 0; i < 16; i++)
                r[i] = *(const usv*)(hb + (size_t)s[i] * F + lane * V);
#pragma unroll
            for (int i = 0; i < 16; i++)
#pragma unroll
                for (int u = 0; u < V; u++) acc[u] += w[i] * bf2f(r[i][u]);
        }
        for (int bse = nfull << 4; bse < cnt; bse += 4) {
            int s[4]; float w[4];
#pragma unroll
            for (int i = 0; i < 4; i++) {
                s[i] = __shfl(srcj, bse + i);
                w[i] = __shfl(ex, bse + i);
            }
            usv r[4];
#pragma unroll
            for (int i = 0; i < 4; i++)
                r[i] = *(const usv*)(hb + (size_t)s[i] * F + lane * V);
#pragma unroll
            for (int i = 0; i < 4; i++)
#pragma unroll
                for (int u = 0; u < V; u++) acc[u] += w[i] * bf2f(r[i][u]);
        }
    }
#pragma unroll
    for (int off = 32; off; off >>= 1) sum += __shfl_xor(sum, off);
    float inv = 1.0f / (sum + 1e-16f);

    fvec r;
#pragma unroll
    for (int u = 0; u < V; u++) {
        float v = acc[u] * inv + bias[lane * V + u];
        r[u] = fmaxf(v, 0.f);
    }
    if (OUTMODE == 0) {
        *(fvec*)(out + (size_t)wid * F + lane * V) = r;
    } else {
        ushort4 hi, lo;
        hi.x = f2bf_rn(r[0]); lo.x = f2bf_rn(r[0] - bf2f(hi.x));
        hi.y = f2bf_rn(r[1]); lo.y = f2bf_rn(r[1] - bf2f(hi.y));
        hi.z = f2bf_rn(r[2]); lo.z = f2bf_rn(r[2] - bf2f(hi.z));
        hi.w = f2bf_rn(r[3]); lo.w = f2bf_rn(r[3] - bf2f(hi.w));
        unsigned short* o = out2 + (size_t)wid * 2 * F;
        *(ushort4*)(o + lane * 4) = hi;
        *(ushort4*)(o + F + lane * 4) = lo;
    }
}

// ---------------------------------------------------------------------------
extern "C" void kernel_launch(void* const* d_in, const int* in_sizes, int n_in,
                              void* d_out, int out_size, void* d_ws, size_t ws_size,
                              hipStream_t stream) {
    const float* x     = (const float*)d_in[0];
    const int*   ei    = (const int*)d_in[1];
    const float* W0    = (const float*)d_in[2];
    const float* b0    = (const float*)d_in[3];
    const float* asrc0 = (const float*)d_in[4];
    const float* adst0 = (const float*)d_in[5];
    const float* W1    = (const float*)d_in[6];
    const float* b1    = (const float*)d_in[7];
    const float* asrc1 = (const float*)d_in[8];
    const float* adst1 = (const float*)d_in[9];
    float* outp = (float*)d_out;

    const int M = BB * NN;  // 40000

    size_t off = 0;
    char* base = (char*)d_ws;
    auto alloc = [&](size_t bytes) {
        void* p = base + off;
        off += (bytes + 255) & ~(size_t)255;
        return p;
    };
    int*   deg        = (int*)alloc((size_t)NN * 4);
    int*   fill       = (int*)alloc((size_t)NN * 4);
    int*   rowstart   = (int*)alloc((size_t)(NN + 1) * 4);
    int*   sorted_src = (int*)alloc((size_t)ETOT * 4);
    unsigned short* A2  = (unsigned short*)alloc((size_t)M * 512 * 2);  // x-split; reused as out0-split
    unsigned short* W02 = (unsigned short*)alloc((size_t)F1 * 512 * 2);
    unsigned short* W12 = (unsigned short*)alloc((size_t)F2 * 512 * 2);
    unsigned short* h   = (unsigned short*)alloc((size_t)M * F1 * 2);   // bf16 pre-agg features
    float* als        = (float*)alloc((size_t)M * 4);
    float* ald        = (float*)alloc((size_t)M * 4);
    unsigned short* zp = (unsigned short*)alloc(2048);                  // zero page for OOB staging

    hipMemsetAsync(deg, 0, (size_t)NN * 4, stream);
    hipMemsetAsync(fill, 0, (size_t)NN * 4, stream);
    hipMemsetAsync(zp, 0, 2048, stream);

    int egrid = (ETOT + 255) / 256;
    count_kernel<<<egrid, 256, 0, stream>>>(ei, deg);
    scan_kernel<<<1, 256, 0, stream>>>(deg, rowstart);
    scatter_kernel<<<egrid, 256, 0, stream>>>(ei, rowstart, fill, sorted_src);

    int mtiles = (M + 127) / 128;          // 313
    int wgrid = (M * 64) / 256;            // 1 wave per (b,node)

    conv_split<<<(M * (F0 / 4) + 255) / 256, 256, 0, stream>>>(x, A2, M, F0);
    conv_split<<<(F1 * (F0 / 4) + 255) / 256, 256, 0, stream>>>(W0, W02, F1, F0);
    conv_split<<<(F2 * (F1 / 4) + 255) / 256, 256, 0, stream>>>(W1, W12, F2, F1);

    // ----- layer 0 -----
    gemm_mfma<<<dim3(mtiles, F1 / 128), 256, 0, stream>>>(A2, W02, h, zp, M, F1, F0);
    al_kernel<F1><<<wgrid, 256, 0, stream>>>(h, asrc0, adst0, als, ald);
    agg_kernel<F1, 1><<<wgrid, 256, 0, stream>>>(h, als, ald, rowstart, sorted_src, b0,
                                                 nullptr, A2 /* out0 split */);

    // ----- layer 1 -----
    gemm_mfma<<<dim3(mtiles, F2 / 128), 256, 0, stream>>>(A2, W12, h, zp, M, F2, F1);
    al_kernel<F2><<<wgrid, 256, 0, stream>>>(h, asrc1, adst1, als, ald);
    agg_kernel<F2, 0><<<wgrid, 256, 0, stream>>>(h, als, ald, rowstart, sorted_src, b1,
                                                 outp, nullptr);
}